// Round 1
// 94.721 us; speedup vs baseline: 1.0111x; 1.0111x over previous
//
#include <hip/hip_runtime.h>

// Quantize x to nearest codeword on the fixed grid g_j = j - 7.5, j in [0,16),
// bit-exactly replicating the reference's fp32 score arithmetic:
//   s_j = 2.0f * fl(x * g_j) - g_j^2 ; argmax with first-max tie-break.
//
// Key optimization vs the 16-way unrolled argmax: the rounded-score winner can
// only ever be one of the TWO codewords adjacent to rint(x). Proof sketch:
// for x in [m-0.5, m+0.5] the exact score gap between the best candidate and
// any third codeword is >= 0.75, while total fp32 rounding error of a score is
// <= ~3e-5 for |x| <= 16. So we evaluate exactly two scores with the SAME
// rounded arithmetic as the reference and arbitrate with strict '>' (a < b
// always, so ties resolve to the lower index = argmax first-max semantics).
// This is bit-identical to the full argmax at ~14 VALU ops/elem instead of ~80.

__device__ __forceinline__ void quant1(float x, float& val, float& idxf) {
    float m  = rintf(x);                             // nearest integer boundary
    float fa = fminf(fmaxf(m + 7.0f, 0.0f), 15.0f);  // candidate idx a (g = m-0.5), clamped
    float fb = fminf(fmaxf(m + 8.0f, 0.0f), 15.0f);  // candidate idx b (g = m+0.5), clamped
    float ga = fa - 7.5f;                            // exact
    float gb = fb - 7.5f;                            // exact
    // Replicate reference rounding: t = fl(x*g) (mul), then fl(2t - g^2).
    // g^2 is exact in fp32 (x.25 values); compiler contraction to
    // fma(2, t, -n) or fma(-g, g, 2t) is bit-identical since 2t and g^2 are exact.
    float sa = 2.0f * (x * ga) - ga * ga;
    float sb = 2.0f * (x * gb) - gb * gb;
    bool t = sb > sa;                                // strict >: tie -> lower index
    val  = t ? gb : ga;                              // grid[idx] == g, exact
    idxf = t ? fb : fa;                              // idx output compared as float
}

__global__ __launch_bounds__(256) void quant4_kernel(const float4* __restrict__ x4,
                                                     float4* __restrict__ val4,
                                                     float4* __restrict__ idx4,
                                                     int nquads) {
    int i = blockIdx.x * blockDim.x + threadIdx.x;
    if (i >= nquads) return;
    float4 x = x4[i];
    float4 v, f;
    quant1(x.x, v.x, f.x);
    quant1(x.y, v.y, f.y);
    quant1(x.z, v.z, f.z);
    quant1(x.w, v.w, f.w);
    val4[i] = v;
    idx4[i] = f;
}

__global__ void quant_tail_kernel(const float* __restrict__ x,
                                  float* __restrict__ val,
                                  float* __restrict__ idxf,
                                  int start, int n) {
    int i = start + blockIdx.x * blockDim.x + threadIdx.x;
    if (i >= n) return;
    float v, f;
    quant1(x[i], v, f);
    val[i] = v;
    idxf[i] = f;
}

extern "C" void kernel_launch(void* const* d_in, const int* in_sizes, int n_in,
                              void* d_out, int out_size, void* d_ws, size_t ws_size,
                              hipStream_t stream) {
    const float* X = (const float*)d_in[0];
    float* out = (float*)d_out;
    const int n = in_sizes[0];          // 8,388,608
    float* vals = out;                  // first n floats: quantized values
    float* idxf = out + n;              // next n floats: indices (as float)

    const int nquads = n / 4;
    const int block = 256;
    const int grid = (nquads + block - 1) / block;   // 8192 blocks at n=8.4M
    quant4_kernel<<<grid, block, 0, stream>>>(
        (const float4*)X, (float4*)vals, (float4*)idxf, nquads);

    const int rem = n - nquads * 4;
    if (rem > 0) {
        quant_tail_kernel<<<1, 64, 0, stream>>>(X, vals, idxf, nquads * 4, n);
    }
}